// Round 8
// baseline (563.717 us; speedup 1.0000x reference)
//
#include <hip/hip_runtime.h>
#include <math.h>

// Problem constants (reference: B=64, T=8192, X=32, fp32)
constexpr int B_   = 64;
constexpr int T_   = 8192;
constexpr int XG   = 8;            // 8 float4 groups per timestep (X=32 floats)
constexpr int SEGS = 32;           // blocks per batch-row b
constexpr int TSEG = T_ / SEGS;    // 256 timesteps per block
constexpr int TC   = 8;            // timesteps per thread (16 float4 resident in regs)
constexpr float NEG_LARGE = -1.0e6f;
constexpr unsigned AGG_MAGIC = 0x1F2E3D4Cu;  // != 0xAAAAAAAA ws-poison

typedef float vf4 __attribute__((ext_vector_type(4)));

// Recurrence: out = min(phi, max(psi, carry)) == clamp(carry; lo=min(phi,psi), hi=phi).
// Clamp monoid: composite == (L,H) = (f(-inf), f(+inf)); apply = min(H, max(L, c)).
// Compose (later g after earlier f): L' = clamp_g(L_f), H' = clamp_g(H_f).
// All ops are exact float selections -> bit-exact vs sequential reference.

__device__ __forceinline__ float4 clamp4(const float4 lo, const float4 hi, const float4 c) {
    return make_float4(fminf(hi.x, fmaxf(lo.x, c.x)),
                       fminf(hi.y, fmaxf(lo.y, c.y)),
                       fminf(hi.z, fmaxf(lo.z, c.z)),
                       fminf(hi.w, fmaxf(lo.w, c.w)));
}

__device__ __forceinline__ void compose_pair(const float4 p, const float4 q,
                                             float4& L, float4& H) {
    float l;
    l = fminf(p.x, q.x); L.x = fminf(p.x, fmaxf(l, L.x)); H.x = fminf(p.x, fmaxf(l, H.x));
    l = fminf(p.y, q.y); L.y = fminf(p.y, fmaxf(l, L.y)); H.y = fminf(p.y, fmaxf(l, H.y));
    l = fminf(p.z, q.z); L.z = fminf(p.z, fmaxf(l, L.z)); H.z = fminf(p.z, fmaxf(l, H.z));
    l = fminf(p.w, q.w); L.w = fminf(p.w, fmaxf(l, L.w)); H.w = fminf(p.w, fmaxf(l, H.w));
}

__device__ __forceinline__ void apply_step(const float4 p, const float4 q, float4& c) {
    c.x = fminf(p.x, fmaxf(q.x, c.x));   // exact reference form
    c.y = fminf(p.y, fmaxf(q.y, c.y));
    c.z = fminf(p.z, fmaxf(q.z, c.z));
    c.w = fminf(p.w, fmaxf(q.w, c.w));
}

__device__ __forceinline__ float4 shfl_up4(const float4 v, int d) {
    return make_float4(__shfl_up(v.x, d, 64), __shfl_up(v.y, d, 64),
                       __shfl_up(v.z, d, 64), __shfl_up(v.w, d, 64));
}

// One kernel: load once into registers -> local scan -> AGG-only decoupled
// lookback (block g waits only on lower-g aggregates; deadlock-free under
// ascending dispatch) -> apply from registers -> nontemporal store.
__global__ __launch_bounds__(256) void until_fused(
        const float4* __restrict__ phi, const float4* __restrict__ psi,
        float4* __restrict__ out, float4* __restrict__ agg,
        unsigned* __restrict__ flags) {
    const int g    = blockIdx.x;          // b*SEGS + seg
    const int b    = g >> 5;              // / SEGS
    const int seg  = g & (SEGS - 1);
    const int tid  = threadIdx.x;
    const int w    = tid >> 6;            // wave 0..3
    const int lane = tid & 63;
    const int jl   = lane >> 3;           // chunk-within-wave 0..7
    const int xg   = lane & 7;            // float4 group 0..7
    const int cb   = w * 8 + jl;          // chunk-within-block 0..31
    const size_t base = ((size_t)b * T_ + (size_t)seg * TSEG + (size_t)cb * TC) * XG + xg;

    __shared__ float4 swL[4][XG];         // per-wave inclusive totals
    __shared__ float4 swH[4][XG];
    __shared__ float4 cLDS[XG];           // block carry-in per xg

    // ---- Phase 1: load this thread's TC=8 timesteps (kept in registers) ----
    float4 p[TC], q[TC];
    #pragma unroll
    for (int k = 0; k < TC; ++k) p[k] = phi[base + (size_t)k * XG];
    #pragma unroll
    for (int k = 0; k < TC; ++k) q[k] = psi[base + (size_t)k * XG];

    // Per-thread clamp summary of its 8 steps.
    float4 L = make_float4(-INFINITY, -INFINITY, -INFINITY, -INFINITY);
    float4 H = make_float4( INFINITY,  INFINITY,  INFINITY,  INFINITY);
    #pragma unroll
    for (int k = 0; k < TC; ++k) compose_pair(p[k], q[k], L, H);

    // ---- Phase 2: wave-inclusive scan over jl (stride-8 lanes, 3 steps) ----
    #pragma unroll
    for (int d = 8; d < 64; d <<= 1) {
        const float4 Lp = shfl_up4(L, d);
        const float4 Hp = shfl_up4(H, d);
        if (lane >= d) {
            const float4 nL = clamp4(L, H, Lp);   // self (later) ∘ prev
            const float4 nH = clamp4(L, H, Hp);
            L = nL; H = nH;
        }
    }

    // ---- Phase 3: cross-wave composition via LDS ----
    if (jl == 7) { swL[w][xg] = L; swH[w][xg] = H; }
    __syncthreads();

    // Wave-exclusive composite (waves < w), per this thread's xg.
    float4 wcL = make_float4(-INFINITY, -INFINITY, -INFINITY, -INFINITY);
    float4 wcH = make_float4( INFINITY,  INFINITY,  INFINITY,  INFINITY);
    for (int ww = 0; ww < w; ++ww) {
        const float4 sL = swL[ww][xg], sH = swH[ww][xg];
        const float4 nL = clamp4(sL, sH, wcL);
        const float4 nH = clamp4(sL, sH, wcH);
        wcL = nL; wcH = nH;
    }

    // ---- Phase 4+5: publish block aggregate; lookback over predecessors ----
    if (tid < 8) {                         // lane == xg == tid
        float4 BL = make_float4(-INFINITY, -INFINITY, -INFINITY, -INFINITY);
        float4 BH = make_float4( INFINITY,  INFINITY,  INFINITY,  INFINITY);
        #pragma unroll
        for (int ww = 0; ww < 4; ++ww) {
            const float4 sL = swL[ww][tid], sH = swH[ww][tid];
            const float4 nL = clamp4(sL, sH, BL);
            const float4 nH = clamp4(sL, sH, BH);
            BL = nL; BH = nH;
        }
        agg[(size_t)g * 16 + tid * 2 + 0] = BL;
        agg[(size_t)g * 16 + tid * 2 + 1] = BH;
        __threadfence();                   // drain payload stores (device scope)
        if (tid == 0)
            __hip_atomic_store(&flags[(size_t)g * 16], AGG_MAGIC,
                               __ATOMIC_RELEASE, __HIP_MEMORY_SCOPE_AGENT);

        // Lookback: compose aggregates of segs seg-1 .. 0 (acc = later composite).
        float4 aL = make_float4(-INFINITY, -INFINITY, -INFINITY, -INFINITY);
        float4 aH = make_float4( INFINITY,  INFINITY,  INFINITY,  INFINITY);
        for (int k = seg - 1; k >= 0; --k) {
            const int gk = g - (seg - k);  // = b*SEGS + k, lower block id
            while (__hip_atomic_load(&flags[(size_t)gk * 16],
                                     __ATOMIC_ACQUIRE, __HIP_MEMORY_SCOPE_AGENT)
                   != AGG_MAGIC) {
                __builtin_amdgcn_s_sleep(1);
            }
            const float4 fL = agg[(size_t)gk * 16 + tid * 2 + 0];
            const float4 fH = agg[(size_t)gk * 16 + tid * 2 + 1];
            const float4 nL = clamp4(aL, aH, fL);   // acc ∘ f_k (f_k earlier)
            const float4 nH = clamp4(aL, aH, fH);
            aL = nL; aH = nH;
        }
        const float4 neg4 = make_float4(NEG_LARGE, NEG_LARGE, NEG_LARGE, NEG_LARGE);
        cLDS[tid] = clamp4(aL, aH, neg4);  // carry value entering this block
    }
    __syncthreads();

    // ---- Phase 6: per-thread carry-in = block-carry -> waves<w -> jl'<jl ----
    float4 c = cLDS[xg];
    c = clamp4(wcL, wcH, c);
    const float4 exL = shfl_up4(L, 8);     // inclusive at jl-1 == exclusive at jl
    const float4 exH = shfl_up4(H, 8);
    if (jl > 0) c = clamp4(exL, exH, c);

    // ---- Phase 7: apply exact recurrence from registers; nontemporal store ----
    #pragma unroll
    for (int k = 0; k < TC; ++k) {
        apply_step(p[k], q[k], c);
        vf4 cv; cv.x = c.x; cv.y = c.y; cv.z = c.z; cv.w = c.w;
        __builtin_nontemporal_store(cv,
            reinterpret_cast<vf4*>(&out[base + (size_t)k * XG]));
    }
}

extern "C" void kernel_launch(void* const* d_in, const int* in_sizes, int n_in,
                              void* d_out, int out_size, void* d_ws, size_t ws_size,
                              hipStream_t stream) {
    const float4* phi = (const float4*)d_in[0];   // trace1
    const float4* psi = (const float4*)d_in[1];   // trace2
    float4* out = (float4*)d_out;

    // ws layout: agg[2048][16] float4 (512 KiB), then flags[2048] at 64 B stride.
    float4*   agg   = (float4*)d_ws;
    unsigned* flags = (unsigned*)((char*)d_ws + (size_t)B_ * SEGS * 16 * sizeof(float4));

    until_fused<<<B_ * SEGS, 256, 0, stream>>>(phi, psi, out, agg, flags);
}